// Round 6
// baseline (62.029 us; speedup 1.0000x reference)
//
#include <hip/hip_runtime.h>
#include <hip/hip_bf16.h>

#define D_MODEL 4096
#define NN      4403      // selected neurons
#define NB      64        // batch
#define TN      16        // neurons per wave (one 16x16 MFMA column tile)
#define KCH     256       // K per wave
#define KSPLIT  (D_MODEL / KCH)           // 16
#define NT      ((NN + TN - 1) / TN)      // 276 neuron tiles
#define OUT_ELEMS (NB * NN)               // 281792
#define WS_NEEDED ((size_t)KSPLIT * OUT_ELEMS * 4)   // ~18 MB

using f32x4  = __attribute__((ext_vector_type(4))) float;
using bf16x8 = __attribute__((ext_vector_type(8))) short;
using u16x8  = __attribute__((ext_vector_type(8))) unsigned short;

__device__ __forceinline__ unsigned short f2bf(float f) {
    __hip_bfloat16 h = __float2bfloat16(f);     // RNE
    return __builtin_bit_cast(unsigned short, h);
}

__device__ __forceinline__ bf16x8 pack8(f32x4 a, f32x4 b) {
    u16x8 v;
    v[0] = f2bf(a[0]); v[1] = f2bf(a[1]); v[2] = f2bf(a[2]); v[3] = f2bf(a[3]);
    v[4] = f2bf(b[0]); v[5] = f2bf(b[1]); v[6] = f2bf(b[2]); v[7] = f2bf(b[3]);
    return __builtin_bit_cast(bf16x8, v);
}

__device__ __forceinline__ f32x4 ntload4(const float* p) {
    return __builtin_nontemporal_load((const f32x4*)p);
}

// One wave per (16-neuron, 256-K) tile. No LDS, no barriers — waves are fully
// independent memory streams. W is nt-streamed (single-use, don't pollute L2);
// X (1 MB fp32) stays L2-resident and is read per-fragment.
template <bool ATOMIC>
__global__ __launch_bounds__(64, 3)
void gather_gemm_nolds(const float* __restrict__ X,
                       const float* __restrict__ W,
                       const int*   __restrict__ idx,
                       float* __restrict__ out)
{
    const int lane = threadIdx.x;      // 0..63
    const int fr   = lane & 15;        // neuron within tile / batch row within m-tile
    const int g    = lane >> 4;        // k-group
    const int fk   = g * 8;

    const int n0    = blockIdx.x * TN;
    const int kbase = blockIdx.y * KCH;

    const int n    = n0 + fr;
    const int wrow = idx[(n < NN) ? n : (NN - 1)];
    const float* wp = W + (size_t)wrow * D_MODEL + kbase + fk;

    // full-depth W prefetch: 8 fragments x 32 B/lane, all in flight at once
    f32x4 wa[8][2];
#pragma unroll
    for (int s = 0; s < 8; ++s) {
        wa[s][0] = ntload4(wp + s * 32);
        wa[s][1] = ntload4(wp + s * 32 + 4);
    }

    f32x4 acc[4];
#pragma unroll
    for (int m = 0; m < 4; ++m) acc[m] = (f32x4){0.f, 0.f, 0.f, 0.f};

    const float* xbase = X + kbase + fk;

#pragma unroll
    for (int s = 0; s < 8; ++s) {
        bf16x8 wf = pack8(wa[s][0], wa[s][1]);
#pragma unroll
        for (int m = 0; m < 4; ++m) {
            const float* xp = xbase + (size_t)(m * 16 + fr) * D_MODEL + s * 32;
            f32x4 a0 = *(const f32x4*)(xp + 0);     // L2-hit: X fits every XCD L2
            f32x4 a1 = *(const f32x4*)(xp + 4);
            acc[m] = __builtin_amdgcn_mfma_f32_16x16x32_bf16(pack8(a0, a1), wf, acc[m], 0, 0, 0);
        }
    }

    // C/D layout: col = lane&15 (neuron), row = (lane>>4)*4 + reg (batch)
    const int ncol = n0 + fr;
    if (ncol < NN) {
        float* base = ATOMIC ? out : out + (size_t)blockIdx.y * OUT_ELEMS;
#pragma unroll
        for (int m = 0; m < 4; ++m) {
            int brow = m * 16 + g * 4;
#pragma unroll
            for (int r = 0; r < 4; ++r) {
                if (ATOMIC)
                    atomicAdd(&base[(size_t)(brow + r) * NN + ncol], acc[m][r]);
                else
                    base[(size_t)(brow + r) * NN + ncol] = acc[m][r];
            }
        }
    }
}

// out[i] = sum_s partial[s][i]   (fully coalesced float4 both ways)
__global__ __launch_bounds__(256)
void reduce_splitk(const float* __restrict__ p, float* __restrict__ out) {
    const int i = blockIdx.x * 256 + threadIdx.x;        // float4 index
    const int n4 = OUT_ELEMS / 4;                        // 70448
    if (i >= n4) return;
    const f32x4* p4 = (const f32x4*)p;
    f32x4 a = p4[i];
#pragma unroll
    for (int s = 1; s < KSPLIT; ++s) a += p4[(size_t)s * n4 + i];
    ((f32x4*)out)[i] = a;
}

extern "C" void kernel_launch(void* const* d_in, const int* in_sizes, int n_in,
                              void* d_out, int out_size, void* d_ws, size_t ws_size,
                              hipStream_t stream) {
    const float* X   = (const float*)d_in[0];   // [64,1,4096] f32
    const float* W   = (const float*)d_in[1];   // [11008,4096] f32
    const int*   idx = (const int*)d_in[2];     // [4403] i32
    float* out = (float*)d_out;                 // [64,1,4403] f32

    dim3 grid(NT, KSPLIT, 1);   // 276 x 16 = 4416 single-wave blocks (~17 waves/CU)

    if (ws_size >= WS_NEEDED) {
        float* partial = (float*)d_ws;
        gather_gemm_nolds<false><<<grid, 64, 0, stream>>>(X, W, idx, partial);
        int n4 = OUT_ELEMS / 4;
        reduce_splitk<<<(n4 + 255) / 256, 256, 0, stream>>>(partial, out);
    } else {
        hipMemsetAsync(d_out, 0, (size_t)out_size * sizeof(float), stream);
        gather_gemm_nolds<true><<<grid, 64, 0, stream>>>(X, W, idx, out);
    }
}

// Round 7
// 30.692 us; speedup vs baseline: 2.0210x; 2.0210x over previous
//
#include <hip/hip_runtime.h>
#include <hip/hip_bf16.h>

#define D_MODEL 4096
#define NN      4403      // selected neurons
#define NB      64        // batch
#define BN      64        // neurons per block (4 waves x 16)
#define KCH     256       // K per block
#define KSPLIT  (D_MODEL / KCH)           // 16
#define NT      ((NN + BN - 1) / BN)      // 69 neuron tiles
#define LDX     264       // shorts per X row in LDS (132 dw ≡ 4 mod 32 -> 2-way max on frag reads)
#define OUT_ELEMS (NB * NN)               // 281792
#define WS_NEEDED ((size_t)KSPLIT * OUT_ELEMS * 4)   // ~18 MB

using f32x4  = __attribute__((ext_vector_type(4))) float;
using bf16x8 = __attribute__((ext_vector_type(8))) short;
using u16x8  = __attribute__((ext_vector_type(8))) unsigned short;

__device__ __forceinline__ unsigned short f2bf(float f) {
    __hip_bfloat16 h = __float2bfloat16(f);     // RNE
    return __builtin_bit_cast(unsigned short, h);
}

__device__ __forceinline__ u16x8 pack8(f32x4 a, f32x4 b) {
    u16x8 v;
    v[0] = f2bf(a[0]); v[1] = f2bf(a[1]); v[2] = f2bf(a[2]); v[3] = f2bf(a[3]);
    v[4] = f2bf(b[0]); v[5] = f2bf(b[1]); v[6] = f2bf(b[2]); v[7] = f2bf(b[3]);
    return v;
}

// Many small decoupled blocks: 4 waves, W-in-regs (full-depth prefetch),
// X bf16 panel in 33 KB LDS (3 blocks/CU resident), one barrier per block.
template <bool ATOMIC>
__global__ __launch_bounds__(256, 3)
void gather_gemm(const float* __restrict__ X,
                 const float* __restrict__ W,
                 const int*   __restrict__ idx,
                 float* __restrict__ out)   // partial base (or out if ATOMIC)
{
    __shared__ __align__(16) unsigned short Xs[64 * LDX];   // 33 KB

    const int tid   = threadIdx.x;
    const int wave  = tid >> 6;
    const int lane  = tid & 63;
    const int fr    = lane & 15;       // neuron within wave tile
    const int g     = lane >> 4;       // k-group
    const int fk    = g * 8;

    const int n0    = blockIdx.x * BN;
    const int kbase = blockIdx.y * KCH;

    // ---- W: full-depth per-lane prefetch (KCH=256 -> 8 fragments, 64 VGPR) ----
    const int n    = n0 + wave * 16 + fr;
    const int wrow = idx[(n < NN) ? n : (NN - 1)];
    const float* wp = W + (size_t)wrow * D_MODEL + kbase + fk;

    f32x4 wa[8][2];
#pragma unroll
    for (int s = 0; s < 8; ++s) {
        wa[s][0] = *(const f32x4*)(wp + s * 32);
        wa[s][1] = *(const f32x4*)(wp + s * 32 + 4);
    }

    // ---- X staging: 64 rows x 256 f32 -> bf16; 32 lanes cover a full row (1 KB contiguous) ----
    {
        const int row8 = tid >> 5;             // 0..7
        const int colf = (tid & 31) * 8;       // float offset within row
#pragma unroll
        for (int p = 0; p < 8; ++p) {
            const int row = p * 8 + row8;
            const float* xp = X + (size_t)row * D_MODEL + kbase + colf;
            f32x4 a = *(const f32x4*)(xp + 0);
            f32x4 b = *(const f32x4*)(xp + 4);
            *(u16x8*)&Xs[row * LDX + colf] = pack8(a, b);
        }
    }
    __syncthreads();   // single drain: all W + X loads retired here

    f32x4 acc[4];
#pragma unroll
    for (int m = 0; m < 4; ++m) acc[m] = (f32x4){0.f, 0.f, 0.f, 0.f};

    // ---- pure regs + LDS + MFMA ----
#pragma unroll
    for (int s = 0; s < 8; ++s) {
        bf16x8 wf = __builtin_bit_cast(bf16x8, pack8(wa[s][0], wa[s][1]));
#pragma unroll
        for (int m = 0; m < 4; ++m) {
            bf16x8 afrag = *(const bf16x8*)&Xs[(m * 16 + fr) * LDX + s * 32 + fk];
            acc[m] = __builtin_amdgcn_mfma_f32_16x16x32_bf16(afrag, wf, acc[m], 0, 0, 0);
        }
    }

    // ---- epilogue: C/D col = lane&15 (neuron), row = (lane>>4)*4 + reg (batch) ----
    const int ncol = n0 + wave * 16 + fr;
    if (ncol < NN) {
        float* base = ATOMIC ? out : out + (size_t)blockIdx.y * OUT_ELEMS;
#pragma unroll
        for (int m = 0; m < 4; ++m) {
            int brow = m * 16 + g * 4;
#pragma unroll
            for (int r = 0; r < 4; ++r) {
                if (ATOMIC)
                    atomicAdd(&base[(size_t)(brow + r) * NN + ncol], acc[m][r]);
                else
                    base[(size_t)(brow + r) * NN + ncol] = acc[m][r];
            }
        }
    }
}

// out[i] = sum_s partial[s][i]   (fully coalesced float4 both ways)
__global__ __launch_bounds__(256)
void reduce_splitk(const float* __restrict__ p, float* __restrict__ out) {
    const int i = blockIdx.x * 256 + threadIdx.x;        // float4 index
    const int n4 = OUT_ELEMS / 4;                        // 70448
    if (i >= n4) return;
    const f32x4* p4 = (const f32x4*)p;
    f32x4 a = p4[i];
#pragma unroll
    for (int s = 1; s < KSPLIT; ++s) a += p4[(size_t)s * n4 + i];
    ((f32x4*)out)[i] = a;
}

extern "C" void kernel_launch(void* const* d_in, const int* in_sizes, int n_in,
                              void* d_out, int out_size, void* d_ws, size_t ws_size,
                              hipStream_t stream) {
    const float* X   = (const float*)d_in[0];   // [64,1,4096] f32
    const float* W   = (const float*)d_in[1];   // [11008,4096] f32
    const int*   idx = (const int*)d_in[2];     // [4403] i32
    float* out = (float*)d_out;                 // [64,1,4403] f32

    dim3 grid(NT, KSPLIT, 1);   // 69 x 16 = 1104 blocks (~4.3/CU, ~3 resident)

    if (ws_size >= WS_NEEDED) {
        float* partial = (float*)d_ws;
        gather_gemm<false><<<grid, 256, 0, stream>>>(X, W, idx, partial);
        int n4 = OUT_ELEMS / 4;
        reduce_splitk<<<(n4 + 255) / 256, 256, 0, stream>>>(partial, out);
    } else {
        hipMemsetAsync(d_out, 0, (size_t)out_size * sizeof(float), stream);
        gather_gemm<true><<<grid, 256, 0, stream>>>(X, W, idx, out);
    }
}